// Round 6
// baseline (260.223 us; speedup 1.0000x reference)
//
#include <hip/hip_runtime.h>
#include <hip/hip_bf16.h>
#include <stdint.h>

#define BATCH 8192
#define DIM   512
#define TILE  128
#define BK    64
#define NT    (BATCH / TILE)          // 64 tiles per dim
#define NPAIR (NT * (NT + 1) / 2)     // 2080 upper-triangle tile pairs

// Fb = F_norm * sqrt(log2(e)/T) so acc = Fb·Fbᵀ is already log2-domain logits.
#define FEAT_SCALE 4.5398164f         // sqrt(1.4426950409/0.07)
#define LN2        0.69314718055994531f

typedef __attribute__((ext_vector_type(8))) short short8;
typedef __attribute__((ext_vector_type(4))) float f32x4;

__device__ __forceinline__ void gld_lds16(const void* g, void* l) {
  __builtin_amdgcn_global_load_lds(
      (__attribute__((address_space(1))) void*)(uintptr_t)g,
      (__attribute__((address_space(3))) void*)(uintptr_t)l,
      16, 0, 0);
}

// ---------------------------------------------------------------------------
// Kernel 1: row-normalize fp32 -> bf16 * FEAT_SCALE. One wave per row.
// Also zeroes rowsum, possimSum, and the completion counter for this launch
// (same-stream kernel-boundary visibility covers the sim kernel's use).
// ---------------------------------------------------------------------------
__global__ __launch_bounds__(256) void normalize_bf16(
    const float* __restrict__ x, __hip_bfloat16* __restrict__ o,
    float* __restrict__ rowsum, float* __restrict__ possimSum,
    int* __restrict__ counter) {
  const int wv = threadIdx.x >> 6, lane = threadIdx.x & 63;
  const int row = blockIdx.x * 4 + wv;
  if (lane == 0) rowsum[row] = 0.0f;
  if (blockIdx.x == 0 && threadIdx.x == 0) { *possimSum = 0.0f; *counter = 0; }
  const float4* xr = (const float4*)(x + (size_t)row * DIM);
  const float4 v0 = xr[lane];
  const float4 v1 = xr[lane + 64];
  float ss = v0.x * v0.x + v0.y * v0.y + v0.z * v0.z + v0.w * v0.w +
             v1.x * v1.x + v1.y * v1.y + v1.z * v1.z + v1.w * v1.w;
#pragma unroll
  for (int m = 32; m > 0; m >>= 1) ss += __shfl_xor(ss, m, 64);
  const float inv = FEAT_SCALE / fmaxf(sqrtf(ss), 1e-12f);
  ushort4 p0, p1;
  p0.x = __bfloat16_as_ushort(__float2bfloat16(v0.x * inv));
  p0.y = __bfloat16_as_ushort(__float2bfloat16(v0.y * inv));
  p0.z = __bfloat16_as_ushort(__float2bfloat16(v0.z * inv));
  p0.w = __bfloat16_as_ushort(__float2bfloat16(v0.w * inv));
  p1.x = __bfloat16_as_ushort(__float2bfloat16(v1.x * inv));
  p1.y = __bfloat16_as_ushort(__float2bfloat16(v1.y * inv));
  p1.z = __bfloat16_as_ushort(__float2bfloat16(v1.z * inv));
  p1.w = __bfloat16_as_ushort(__float2bfloat16(v1.w * inv));
  ushort4* orow = (ushort4*)(o + (size_t)row * DIM);
  orow[lane]      = p0;
  orow[lane + 64] = p1;
}

// ---------------------------------------------------------------------------
// Kernel 2: R0-proven core (verbatim): symmetric 128x128 bf16 MFMA tiles,
// upper triangle, natural block order, single-buffer LDS, 2 syncthreads per
// K-step, 2.5-4 co-resident blocks/CU (the mechanism that wins at this size).
// New this round: positives reduced in-block to a single device-scope
// atomicAdd(possimSum); a completion counter makes the LAST block compute
// the final loss (removes the finalize kernel + one launch overhead).
// ---------------------------------------------------------------------------
__global__ __launch_bounds__(256, 4) void sim_lse_kernel(
    const __hip_bfloat16* __restrict__ F, float* __restrict__ rowsum,
    float* __restrict__ possimSum, int* __restrict__ counter,
    float* __restrict__ out) {
  __shared__ __hip_bfloat16 smem[2 * TILE * BK];  // 32 KB staging; reused by epilogue
  __shared__ float colAcc[TILE];
  __shared__ float posSh;
  __shared__ int lastFlag;

  const int t = blockIdx.x;
  int by = (int)((129.0f - sqrtf(129.0f * 129.0f - 8.0f * (float)t)) * 0.5f);
  if (by > NT - 1) by = NT - 1;
  if (by < 0) by = 0;
  while ((by + 1) * (129 - (by + 1)) / 2 <= t) ++by;
  while (by * (129 - by) / 2 > t) --by;
  const int bx = by + (t - by * (129 - by) / 2);
  const bool diagTile = (bx == by);
  const bool hasPos = (bx == by + 32);

  const int rowBase = by * TILE;
  const int colBase = bx * TILE;

  const int tid   = threadIdx.x;
  const int lane  = tid & 63;
  const int wv    = tid >> 6;
  const int waveM = wv >> 1;
  const int waveN = wv & 1;
  const int quad  = lane >> 4;
  const int l15   = lane & 15;

  if (tid < TILE) colAcc[tid] = 0.0f;
  if (tid == 0) posSh = 0.0f;

  f32x4 acc[4][4] = {};

  const int sb = lane & 7;
  const __hip_bfloat16* gA[4];
  const __hip_bfloat16* gB[4];
  char* ldsA[4];
  char* ldsB[4];
#pragma unroll
  for (int c = 0; c < 4; ++c) {
    const int sRow = wv * 32 + c * 8 + (lane >> 3);
    const int g = sb ^ (sRow & 7);
    gA[c] = F + (size_t)(rowBase + sRow) * DIM + g * 8;
    gB[c] = F + (size_t)(colBase + sRow) * DIM + g * 8;
    ldsA[c] = (char*)smem + (wv * 4 + c) * 1024;
    ldsB[c] = (char*)smem + 16384 + (wv * 4 + c) * 1024;
  }

  int aOff[4], bOff[4];
#pragma unroll
  for (int i = 0; i < 4; ++i) {
    const int Ra = waveM * 64 + i * 16 + l15;
    aOff[i] = Ra * 128 + (quad ^ (Ra & 7)) * 16;
    const int Rb = waveN * 64 + i * 16 + l15;
    bOff[i] = 16384 + Rb * 128 + (quad ^ (Rb & 7)) * 16;
  }
  char* sbase = (char*)smem;

  for (int k0 = 0; k0 < DIM; k0 += BK) {
#pragma unroll
    for (int c = 0; c < 4; ++c) {
      gld_lds16(gA[c] + k0, ldsA[c]);
      gld_lds16(gB[c] + k0, ldsB[c]);
    }
    __syncthreads();

    short8 a[4], b[4];
#pragma unroll
    for (int i = 0; i < 4; ++i) {
      a[i] = *(const short8*)(sbase + aOff[i]);
      b[i] = *(const short8*)(sbase + bOff[i]);
    }
#pragma unroll
    for (int mi = 0; mi < 4; ++mi)
#pragma unroll
      for (int ni = 0; ni < 4; ++ni)
        acc[mi][ni] =
            __builtin_amdgcn_mfma_f32_16x16x32_bf16(a[mi], b[ni], acc[mi][ni], 0, 0, 0);
#pragma unroll
    for (int i = 0; i < 4; ++i) {
      a[i] = *(const short8*)(sbase + (aOff[i] ^ 64));
      b[i] = *(const short8*)(sbase + (bOff[i] ^ 64));
    }
#pragma unroll
    for (int mi = 0; mi < 4; ++mi)
#pragma unroll
      for (int ni = 0; ni < 4; ++ni)
        acc[mi][ni] =
            __builtin_amdgcn_mfma_f32_16x16x32_bf16(a[mi], b[ni], acc[mi][ni], 0, 0, 0);
    __syncthreads();   // after this, smem staging data is dead -> reuse below
  }

  // --- epilogue ---
  // redBuf overlays smem: [wn][strip][l15][68 dw], 2*2*16*68*4 = 17408 B.
  float* redBuf = (float*)smem;
  f32x4 rsumv[4] = {};                 // per-lane row partials
  float colpart[4] = {0.0f, 0.0f, 0.0f, 0.0f};
  float posAcc = 0.0f;

  if (diagTile) {
#pragma unroll
    for (int mi = 0; mi < 4; ++mi)
#pragma unroll
      for (int ni = 0; ni < 4; ++ni)
#pragma unroll
        for (int r = 0; r < 4; ++r) {
          const int rl = waveM * 64 + mi * 16 + quad * 4 + r;
          const int cl = waveN * 64 + ni * 16 + l15;
          rsumv[mi][r] += (cl == rl) ? 0.0f : exp2f(acc[mi][ni][r]);
        }
  } else {
#pragma unroll
    for (int mi = 0; mi < 4; ++mi)
#pragma unroll
      for (int ni = 0; ni < 4; ++ni)
#pragma unroll
        for (int r = 0; r < 4; ++r) {
          const float s = acc[mi][ni][r];
          const float e = exp2f(s);
          rsumv[mi][r] += e;
          colpart[ni] += e;
          if (hasPos) {
            const int rl = waveM * 64 + mi * 16 + quad * 4 + r;
            const int cl = waveN * 64 + ni * 16 + l15;
            if (cl == rl) posAcc += s;   // diagonal sim: pair (i, i+4096)
          }
        }
  }

  // transpose-store row partials: lane -> [waveN][waveM][l15][mi*16+quad*4 .. +3]
  {
    float* wbase = redBuf + ((waveN * 2 + waveM) * 16 + l15) * 68 + quad * 4;
#pragma unroll
    for (int mi = 0; mi < 4; ++mi)
      *(f32x4*)(wbase + mi * 16) = rsumv[mi];
  }

  // col sums (symmetry credit): reduce over quads, combine waveM pair in LDS
  if (!diagTile) {
#pragma unroll
    for (int ni = 0; ni < 4; ++ni) {
      float c = colpart[ni];
      c += __shfl_xor(c, 16, 64);
      c += __shfl_xor(c, 32, 64);
      if (quad == 0) atomicAdd(&colAcc[waveN * 64 + ni * 16 + l15], c);
    }
  }
  // positives: reduce in-wave, combine in LDS
  if (hasPos) {
    float p = posAcc;
#pragma unroll
    for (int m = 32; m > 0; m >>= 1) p += __shfl_xor(p, m, 64);
    if (lane == 0) atomicAdd(&posSh, p);
  }
  __syncthreads();

  // 256 threads: each sums one (row, waveN-half) = 16 strided floats
  {
    const int wn = tid >> 7, r = tid & 127;
    const int strip = r >> 6, rl = r & 63;
    const float* base = redBuf + ((wn * 2 + strip) * 16) * 68 + rl;
    float s = 0.0f;
#pragma unroll
    for (int j = 0; j < 16; ++j) s += base[j * 68];
    atomicAdd(&rowsum[rowBase + r], s);
  }
  if (tid < TILE && !diagTile)
    atomicAdd(&rowsum[colBase + tid], colAcc[tid]);
  if (tid == 0 && hasPos)
    atomicAdd(possimSum, 2.0f * posSh);   // each diag sim counts for 2 rows

  // --- completion counter: last block computes the loss ---
  __syncthreads();          // drains all this block's global atomics (vmcnt 0)
  __threadfence();          // order them before the counter RMW
  if (tid == 0)
    lastFlag = (atomicAdd(counter, 1) == NPAIR - 1) ? 1 : 0;
  __syncthreads();

  if (lastFlag) {
    // All 2079 other blocks' rowsum/possimSum RMWs are ordered before their
    // counter RMWs; agent-scope atomic loads read the coherence point.
    float av = 0.0f;
    for (int i = tid; i < BATCH; i += 256) {
      const float rs = __hip_atomic_load(&rowsum[i], __ATOMIC_RELAXED,
                                         __HIP_MEMORY_SCOPE_AGENT);
      av += __logf(rs);
    }
#pragma unroll
    for (int m = 32; m > 0; m >>= 1) av += __shfl_xor(av, m, 64);
    if (lane == 0) colAcc[wv] = av;      // colAcc dead; reuse for 4 wave sums
    __syncthreads();
    if (tid == 0) {
      const float tot = colAcc[0] + colAcc[1] + colAcc[2] + colAcc[3];
      const float ps = __hip_atomic_load(possimSum, __ATOMIC_RELAXED,
                                         __HIP_MEMORY_SCOPE_AGENT);
      out[0] = (tot - ps * LN2) * (1.0f / (float)BATCH);
    }
  }
}

extern "C" void kernel_launch(void* const* d_in, const int* in_sizes, int n_in,
                              void* d_out, int out_size, void* d_ws, size_t ws_size,
                              hipStream_t stream) {
  const float* x = (const float*)d_in[0];
  float* out = (float*)d_out;

  __hip_bfloat16* Fb = (__hip_bfloat16*)d_ws;
  float* rowsum = (float*)((char*)d_ws + (size_t)BATCH * DIM * sizeof(__hip_bfloat16));
  float* possimSum = rowsum + BATCH;
  int* counter = (int*)(possimSum + 1);

  normalize_bf16<<<BATCH / 4, 256, 0, stream>>>(x, Fb, rowsum, possimSum, counter);
  sim_lse_kernel<<<NPAIR, 256, 0, stream>>>(Fb, rowsum, possimSum, counter, out);
}

// Round 7
// 124.582 us; speedup vs baseline: 2.0888x; 2.0888x over previous
//
#include <hip/hip_runtime.h>
#include <hip/hip_bf16.h>
#include <stdint.h>

#define BATCH 8192
#define DIM   512
#define TILE  128
#define BK    64
#define NT    (BATCH / TILE)          // 64 tiles per dim
#define NPAIR (NT * (NT + 1) / 2)     // 2080 upper-triangle tile pairs

// Fb = F_norm * sqrt(log2(e)/T) so acc = Fb·Fbᵀ is already log2-domain logits.
#define FEAT_SCALE 4.5398164f         // sqrt(1.4426950409/0.07)
#define LN2        0.69314718055994531f

typedef __attribute__((ext_vector_type(8))) short short8;
typedef __attribute__((ext_vector_type(4))) float f32x4;

__device__ __forceinline__ void gld_lds16(const void* g, void* l) {
  __builtin_amdgcn_global_load_lds(
      (__attribute__((address_space(1))) void*)(uintptr_t)g,
      (__attribute__((address_space(3))) void*)(uintptr_t)l,
      16, 0, 0);
}

// ---------------------------------------------------------------------------
// Kernel 1: row-normalize fp32 -> bf16 * FEAT_SCALE. One wave per row.
// Also zeroes rowsum, possimSum, and the completion counter for this launch
// (same-stream kernel-boundary visibility covers the sim kernel's use).
// ---------------------------------------------------------------------------
__global__ __launch_bounds__(256) void normalize_bf16(
    const float* __restrict__ x, __hip_bfloat16* __restrict__ o,
    float* __restrict__ rowsum, float* __restrict__ possimSum,
    int* __restrict__ counter) {
  const int wv = threadIdx.x >> 6, lane = threadIdx.x & 63;
  const int row = blockIdx.x * 4 + wv;
  if (lane == 0) rowsum[row] = 0.0f;
  if (blockIdx.x == 0 && threadIdx.x == 0) { *possimSum = 0.0f; *counter = 0; }
  const float4* xr = (const float4*)(x + (size_t)row * DIM);
  const float4 v0 = xr[lane];
  const float4 v1 = xr[lane + 64];
  float ss = v0.x * v0.x + v0.y * v0.y + v0.z * v0.z + v0.w * v0.w +
             v1.x * v1.x + v1.y * v1.y + v1.z * v1.z + v1.w * v1.w;
#pragma unroll
  for (int m = 32; m > 0; m >>= 1) ss += __shfl_xor(ss, m, 64);
  const float inv = FEAT_SCALE / fmaxf(sqrtf(ss), 1e-12f);
  ushort4 p0, p1;
  p0.x = __bfloat16_as_ushort(__float2bfloat16(v0.x * inv));
  p0.y = __bfloat16_as_ushort(__float2bfloat16(v0.y * inv));
  p0.z = __bfloat16_as_ushort(__float2bfloat16(v0.z * inv));
  p0.w = __bfloat16_as_ushort(__float2bfloat16(v0.w * inv));
  p1.x = __bfloat16_as_ushort(__float2bfloat16(v1.x * inv));
  p1.y = __bfloat16_as_ushort(__float2bfloat16(v1.y * inv));
  p1.z = __bfloat16_as_ushort(__float2bfloat16(v1.z * inv));
  p1.w = __bfloat16_as_ushort(__float2bfloat16(v1.w * inv));
  ushort4* orow = (ushort4*)(o + (size_t)row * DIM);
  orow[lane]      = p0;
  orow[lane + 64] = p1;
}

// ---------------------------------------------------------------------------
// Kernel 2: R0-proven core (verbatim): symmetric 128x128 bf16 MFMA tiles,
// upper triangle, natural block order, single-buffer LDS, 2 syncthreads per
// K-step, multi-block co-residency. Fused finalize: positives reduced
// in-block to one device-scope atomicAdd(possimSum); completion counter
// makes the LAST block compute the final loss.
//
// NO __threadfence() (round-6 lesson: agent-scope fence emits buffer_wbl2
// -> L2-writeback storm, 4.4x slowdown). Ordering argument without it:
// every cross-block value (rowsum, possimSum) is written ONLY via
// device-scope atomicAdd (performed at the device coherence point, never
// dirty in a local L2). __syncthreads() before the counter add drains
// vmcnt(0), i.e. those atomics are performed; the counter RMW follows.
// The winner block's readback uses agent-scope atomic loads (coherence
// point), issued after its own counter RMW returned.
// ---------------------------------------------------------------------------
__global__ __launch_bounds__(256, 4) void sim_lse_kernel(
    const __hip_bfloat16* __restrict__ F, float* __restrict__ rowsum,
    float* __restrict__ possimSum, int* __restrict__ counter,
    float* __restrict__ out) {
  __shared__ __hip_bfloat16 smem[2 * TILE * BK];  // 32 KB staging; reused by epilogue
  __shared__ float colAcc[TILE];
  __shared__ float posSh;
  __shared__ int lastFlag;

  const int t = blockIdx.x;
  int by = (int)((129.0f - sqrtf(129.0f * 129.0f - 8.0f * (float)t)) * 0.5f);
  if (by > NT - 1) by = NT - 1;
  if (by < 0) by = 0;
  while ((by + 1) * (129 - (by + 1)) / 2 <= t) ++by;
  while (by * (129 - by) / 2 > t) --by;
  const int bx = by + (t - by * (129 - by) / 2);
  const bool diagTile = (bx == by);
  const bool hasPos = (bx == by + 32);

  const int rowBase = by * TILE;
  const int colBase = bx * TILE;

  const int tid   = threadIdx.x;
  const int lane  = tid & 63;
  const int wv    = tid >> 6;
  const int waveM = wv >> 1;
  const int waveN = wv & 1;
  const int quad  = lane >> 4;
  const int l15   = lane & 15;

  if (tid < TILE) colAcc[tid] = 0.0f;
  if (tid == 0) posSh = 0.0f;

  f32x4 acc[4][4] = {};

  const int sb = lane & 7;
  const __hip_bfloat16* gA[4];
  const __hip_bfloat16* gB[4];
  char* ldsA[4];
  char* ldsB[4];
#pragma unroll
  for (int c = 0; c < 4; ++c) {
    const int sRow = wv * 32 + c * 8 + (lane >> 3);
    const int g = sb ^ (sRow & 7);
    gA[c] = F + (size_t)(rowBase + sRow) * DIM + g * 8;
    gB[c] = F + (size_t)(colBase + sRow) * DIM + g * 8;
    ldsA[c] = (char*)smem + (wv * 4 + c) * 1024;
    ldsB[c] = (char*)smem + 16384 + (wv * 4 + c) * 1024;
  }

  int aOff[4], bOff[4];
#pragma unroll
  for (int i = 0; i < 4; ++i) {
    const int Ra = waveM * 64 + i * 16 + l15;
    aOff[i] = Ra * 128 + (quad ^ (Ra & 7)) * 16;
    const int Rb = waveN * 64 + i * 16 + l15;
    bOff[i] = 16384 + Rb * 128 + (quad ^ (Rb & 7)) * 16;
  }
  char* sbase = (char*)smem;

  for (int k0 = 0; k0 < DIM; k0 += BK) {
#pragma unroll
    for (int c = 0; c < 4; ++c) {
      gld_lds16(gA[c] + k0, ldsA[c]);
      gld_lds16(gB[c] + k0, ldsB[c]);
    }
    __syncthreads();

    short8 a[4], b[4];
#pragma unroll
    for (int i = 0; i < 4; ++i) {
      a[i] = *(const short8*)(sbase + aOff[i]);
      b[i] = *(const short8*)(sbase + bOff[i]);
    }
#pragma unroll
    for (int mi = 0; mi < 4; ++mi)
#pragma unroll
      for (int ni = 0; ni < 4; ++ni)
        acc[mi][ni] =
            __builtin_amdgcn_mfma_f32_16x16x32_bf16(a[mi], b[ni], acc[mi][ni], 0, 0, 0);
#pragma unroll
    for (int i = 0; i < 4; ++i) {
      a[i] = *(const short8*)(sbase + (aOff[i] ^ 64));
      b[i] = *(const short8*)(sbase + (bOff[i] ^ 64));
    }
#pragma unroll
    for (int mi = 0; mi < 4; ++mi)
#pragma unroll
      for (int ni = 0; ni < 4; ++ni)
        acc[mi][ni] =
            __builtin_amdgcn_mfma_f32_16x16x32_bf16(a[mi], b[ni], acc[mi][ni], 0, 0, 0);
    __syncthreads();   // after this, smem staging data is dead -> reuse below
  }

  // --- epilogue ---
  // redBuf overlays smem: [wn][strip][l15][68 dw], 2*2*16*68*4 = 17408 B.
  float* redBuf = (float*)smem;
  f32x4 rsumv[4] = {};                 // per-lane row partials
  float colpart[4] = {0.0f, 0.0f, 0.0f, 0.0f};
  float posAcc = 0.0f;

  if (diagTile) {
#pragma unroll
    for (int mi = 0; mi < 4; ++mi)
#pragma unroll
      for (int ni = 0; ni < 4; ++ni)
#pragma unroll
        for (int r = 0; r < 4; ++r) {
          const int rl = waveM * 64 + mi * 16 + quad * 4 + r;
          const int cl = waveN * 64 + ni * 16 + l15;
          rsumv[mi][r] += (cl == rl) ? 0.0f : exp2f(acc[mi][ni][r]);
        }
  } else {
#pragma unroll
    for (int mi = 0; mi < 4; ++mi)
#pragma unroll
      for (int ni = 0; ni < 4; ++ni)
#pragma unroll
        for (int r = 0; r < 4; ++r) {
          const float s = acc[mi][ni][r];
          const float e = exp2f(s);
          rsumv[mi][r] += e;
          colpart[ni] += e;
          if (hasPos) {
            const int rl = waveM * 64 + mi * 16 + quad * 4 + r;
            const int cl = waveN * 64 + ni * 16 + l15;
            if (cl == rl) posAcc += s;   // diagonal sim: pair (i, i+4096)
          }
        }
  }

  // transpose-store row partials: lane -> [waveN][waveM][l15][mi*16+quad*4 .. +3]
  {
    float* wbase = redBuf + ((waveN * 2 + waveM) * 16 + l15) * 68 + quad * 4;
#pragma unroll
    for (int mi = 0; mi < 4; ++mi)
      *(f32x4*)(wbase + mi * 16) = rsumv[mi];
  }

  // col sums (symmetry credit): reduce over quads, combine waveM pair in LDS
  if (!diagTile) {
#pragma unroll
    for (int ni = 0; ni < 4; ++ni) {
      float c = colpart[ni];
      c += __shfl_xor(c, 16, 64);
      c += __shfl_xor(c, 32, 64);
      if (quad == 0) atomicAdd(&colAcc[waveN * 64 + ni * 16 + l15], c);
    }
  }
  // positives: reduce in-wave, combine in LDS
  if (hasPos) {
    float p = posAcc;
#pragma unroll
    for (int m = 32; m > 0; m >>= 1) p += __shfl_xor(p, m, 64);
    if (lane == 0) atomicAdd(&posSh, p);
  }
  __syncthreads();

  // 256 threads: each sums one (row, waveN-half) = 16 strided floats
  {
    const int wn = tid >> 7, r = tid & 127;
    const int strip = r >> 6, rl = r & 63;
    const float* base = redBuf + ((wn * 2 + strip) * 16) * 68 + rl;
    float s = 0.0f;
#pragma unroll
    for (int j = 0; j < 16; ++j) s += base[j * 68];
    atomicAdd(&rowsum[rowBase + r], s);
  }
  if (tid < TILE && !diagTile)
    atomicAdd(&rowsum[colBase + tid], colAcc[tid]);
  if (tid == 0 && hasPos)
    atomicAdd(possimSum, 2.0f * posSh);   // each diag sim counts for 2 rows

  // --- completion counter: last block computes the loss ---
  // __syncthreads drains vmcnt(0): this block's device-scope atomics are
  // performed at the coherence point before the counter RMW below. No
  // __threadfence here (it would emit buffer_wbl2 -> R6's 4.4x regression).
  __syncthreads();
  if (tid == 0)
    lastFlag = (atomicAdd(counter, 1) == NPAIR - 1) ? 1 : 0;
  __syncthreads();

  if (lastFlag) {
    float av = 0.0f;
    for (int i = tid; i < BATCH; i += 256) {
      const float rs = __hip_atomic_load(&rowsum[i], __ATOMIC_RELAXED,
                                         __HIP_MEMORY_SCOPE_AGENT);
      av += __logf(rs);
    }
#pragma unroll
    for (int m = 32; m > 0; m >>= 1) av += __shfl_xor(av, m, 64);
    if (lane == 0) colAcc[wv] = av;      // colAcc dead; reuse for 4 wave sums
    __syncthreads();
    if (tid == 0) {
      const float tot = colAcc[0] + colAcc[1] + colAcc[2] + colAcc[3];
      const float ps = __hip_atomic_load(possimSum, __ATOMIC_RELAXED,
                                         __HIP_MEMORY_SCOPE_AGENT);
      out[0] = (tot - ps * LN2) * (1.0f / (float)BATCH);
    }
  }
}

extern "C" void kernel_launch(void* const* d_in, const int* in_sizes, int n_in,
                              void* d_out, int out_size, void* d_ws, size_t ws_size,
                              hipStream_t stream) {
  const float* x = (const float*)d_in[0];
  float* out = (float*)d_out;

  __hip_bfloat16* Fb = (__hip_bfloat16*)d_ws;
  float* rowsum = (float*)((char*)d_ws + (size_t)BATCH * DIM * sizeof(__hip_bfloat16));
  float* possimSum = rowsum + BATCH;
  int* counter = (int*)(possimSum + 1);

  normalize_bf16<<<BATCH / 4, 256, 0, stream>>>(x, Fb, rowsum, possimSum, counter);
  sim_lse_kernel<<<NPAIR, 256, 0, stream>>>(Fb, rowsum, possimSum, counter, out);
}

// Round 8
// 119.749 us; speedup vs baseline: 2.1731x; 1.0404x over previous
//
#include <hip/hip_runtime.h>
#include <hip/hip_bf16.h>
#include <stdint.h>

#define BATCH 8192
#define DIM   512
#define TILE  128
#define BK    64
#define NT    (BATCH / TILE)          // 64 tiles per dim
#define NPAIR (NT * (NT + 1) / 2)     // 2080 upper-triangle tile pairs

// Fb = F_norm * sqrt(log2(e)/T) so acc = Fb·Fbᵀ is already log2-domain logits.
#define FEAT_SCALE 4.5398164f         // sqrt(1.4426950409/0.07)
#define LN2        0.69314718055994531f

typedef __attribute__((ext_vector_type(8))) short short8;
typedef __attribute__((ext_vector_type(4))) float f32x4;

__device__ __forceinline__ void gld_lds16(const void* g, void* l) {
  __builtin_amdgcn_global_load_lds(
      (__attribute__((address_space(1))) void*)(uintptr_t)g,
      (__attribute__((address_space(3))) void*)(uintptr_t)l,
      16, 0, 0);
}

// ---------------------------------------------------------------------------
// Kernel 1: row-normalize fp32 -> bf16 * FEAT_SCALE. One wave per row.
// Also zeroes rowsum, possimSum, and the completion counter for this launch
// (same-stream kernel-boundary visibility covers the sim kernel's use).
// ---------------------------------------------------------------------------
__global__ __launch_bounds__(256) void normalize_bf16(
    const float* __restrict__ x, __hip_bfloat16* __restrict__ o,
    float* __restrict__ rowsum, float* __restrict__ possimSum,
    int* __restrict__ counter) {
  const int wv = threadIdx.x >> 6, lane = threadIdx.x & 63;
  const int row = blockIdx.x * 4 + wv;
  if (lane == 0) rowsum[row] = 0.0f;
  if (blockIdx.x == 0 && threadIdx.x == 0) { *possimSum = 0.0f; *counter = 0; }
  const float4* xr = (const float4*)(x + (size_t)row * DIM);
  const float4 v0 = xr[lane];
  const float4 v1 = xr[lane + 64];
  float ss = v0.x * v0.x + v0.y * v0.y + v0.z * v0.z + v0.w * v0.w +
             v1.x * v1.x + v1.y * v1.y + v1.z * v1.z + v1.w * v1.w;
#pragma unroll
  for (int m = 32; m > 0; m >>= 1) ss += __shfl_xor(ss, m, 64);
  const float inv = FEAT_SCALE / fmaxf(sqrtf(ss), 1e-12f);
  ushort4 p0, p1;
  p0.x = __bfloat16_as_ushort(__float2bfloat16(v0.x * inv));
  p0.y = __bfloat16_as_ushort(__float2bfloat16(v0.y * inv));
  p0.z = __bfloat16_as_ushort(__float2bfloat16(v0.z * inv));
  p0.w = __bfloat16_as_ushort(__float2bfloat16(v0.w * inv));
  p1.x = __bfloat16_as_ushort(__float2bfloat16(v1.x * inv));
  p1.y = __bfloat16_as_ushort(__float2bfloat16(v1.y * inv));
  p1.z = __bfloat16_as_ushort(__float2bfloat16(v1.z * inv));
  p1.w = __bfloat16_as_ushort(__float2bfloat16(v1.w * inv));
  ushort4* orow = (ushort4*)(o + (size_t)row * DIM);
  orow[lane]      = p0;
  orow[lane + 64] = p1;
}

// ---------------------------------------------------------------------------
// Kernel 2: R0-proven core (verbatim) + fused finalize.
//
// Ordering (no __threadfence -- R6: agent fence by 256 threads/block emits
// buffer_wbl2 storms, 4.4x): all cross-block values (rowsum, possimSum) are
// written ONLY via device-scope atomicAdd (memory-side, non-allocating,
// performed at the coherence point -- proven cross-XCD by R7 passing).
// __syncthreads before the counter RMW drains vmcnt(0) => this block's data
// atomics are performed before its counter increment. The winner (RMW #2080)
// therefore observes all contributions.
//
// R7 lesson: winner readback via __hip_atomic_load(AGENT) = uncached serial
// ~900cy loads => ~33us idle tail (counters: all pipes diluted by exactly
// dur ratio). Fix: PLAIN coalesced float4 loads. Safe because no plain
// access ever allocates rowsum/possimSum lines in any L1/L2 during this
// kernel (only non-allocating atomics touch them; normalize's zero-stores
// flushed at kernel-boundary), so plain loads miss to the coherence point.
// ---------------------------------------------------------------------------
__global__ __launch_bounds__(256, 4) void sim_lse_kernel(
    const __hip_bfloat16* __restrict__ F, float* __restrict__ rowsum,
    float* __restrict__ possimSum, int* __restrict__ counter,
    float* __restrict__ out) {
  __shared__ __hip_bfloat16 smem[2 * TILE * BK];  // 32 KB staging; reused by epilogue
  __shared__ float colAcc[TILE];
  __shared__ float posSh;
  __shared__ int lastFlag;

  const int t = blockIdx.x;
  int by = (int)((129.0f - sqrtf(129.0f * 129.0f - 8.0f * (float)t)) * 0.5f);
  if (by > NT - 1) by = NT - 1;
  if (by < 0) by = 0;
  while ((by + 1) * (129 - (by + 1)) / 2 <= t) ++by;
  while (by * (129 - by) / 2 > t) --by;
  const int bx = by + (t - by * (129 - by) / 2);
  const bool diagTile = (bx == by);
  const bool hasPos = (bx == by + 32);

  const int rowBase = by * TILE;
  const int colBase = bx * TILE;

  const int tid   = threadIdx.x;
  const int lane  = tid & 63;
  const int wv    = tid >> 6;
  const int waveM = wv >> 1;
  const int waveN = wv & 1;
  const int quad  = lane >> 4;
  const int l15   = lane & 15;

  if (tid < TILE) colAcc[tid] = 0.0f;
  if (tid == 0) posSh = 0.0f;

  f32x4 acc[4][4] = {};

  const int sb = lane & 7;
  const __hip_bfloat16* gA[4];
  const __hip_bfloat16* gB[4];
  char* ldsA[4];
  char* ldsB[4];
#pragma unroll
  for (int c = 0; c < 4; ++c) {
    const int sRow = wv * 32 + c * 8 + (lane >> 3);
    const int g = sb ^ (sRow & 7);
    gA[c] = F + (size_t)(rowBase + sRow) * DIM + g * 8;
    gB[c] = F + (size_t)(colBase + sRow) * DIM + g * 8;
    ldsA[c] = (char*)smem + (wv * 4 + c) * 1024;
    ldsB[c] = (char*)smem + 16384 + (wv * 4 + c) * 1024;
  }

  int aOff[4], bOff[4];
#pragma unroll
  for (int i = 0; i < 4; ++i) {
    const int Ra = waveM * 64 + i * 16 + l15;
    aOff[i] = Ra * 128 + (quad ^ (Ra & 7)) * 16;
    const int Rb = waveN * 64 + i * 16 + l15;
    bOff[i] = 16384 + Rb * 128 + (quad ^ (Rb & 7)) * 16;
  }
  char* sbase = (char*)smem;

  for (int k0 = 0; k0 < DIM; k0 += BK) {
#pragma unroll
    for (int c = 0; c < 4; ++c) {
      gld_lds16(gA[c] + k0, ldsA[c]);
      gld_lds16(gB[c] + k0, ldsB[c]);
    }
    __syncthreads();

    short8 a[4], b[4];
#pragma unroll
    for (int i = 0; i < 4; ++i) {
      a[i] = *(const short8*)(sbase + aOff[i]);
      b[i] = *(const short8*)(sbase + bOff[i]);
    }
#pragma unroll
    for (int mi = 0; mi < 4; ++mi)
#pragma unroll
      for (int ni = 0; ni < 4; ++ni)
        acc[mi][ni] =
            __builtin_amdgcn_mfma_f32_16x16x32_bf16(a[mi], b[ni], acc[mi][ni], 0, 0, 0);
#pragma unroll
    for (int i = 0; i < 4; ++i) {
      a[i] = *(const short8*)(sbase + (aOff[i] ^ 64));
      b[i] = *(const short8*)(sbase + (bOff[i] ^ 64));
    }
#pragma unroll
    for (int mi = 0; mi < 4; ++mi)
#pragma unroll
      for (int ni = 0; ni < 4; ++ni)
        acc[mi][ni] =
            __builtin_amdgcn_mfma_f32_16x16x32_bf16(a[mi], b[ni], acc[mi][ni], 0, 0, 0);
    __syncthreads();   // after this, smem staging data is dead -> reuse below
  }

  // --- epilogue ---
  // redBuf overlays smem: [wn][strip][l15][68 dw], 2*2*16*68*4 = 17408 B.
  float* redBuf = (float*)smem;
  f32x4 rsumv[4] = {};                 // per-lane row partials
  float colpart[4] = {0.0f, 0.0f, 0.0f, 0.0f};
  float posAcc = 0.0f;

  if (diagTile) {
#pragma unroll
    for (int mi = 0; mi < 4; ++mi)
#pragma unroll
      for (int ni = 0; ni < 4; ++ni)
#pragma unroll
        for (int r = 0; r < 4; ++r) {
          const int rl = waveM * 64 + mi * 16 + quad * 4 + r;
          const int cl = waveN * 64 + ni * 16 + l15;
          rsumv[mi][r] += (cl == rl) ? 0.0f : exp2f(acc[mi][ni][r]);
        }
  } else {
#pragma unroll
    for (int mi = 0; mi < 4; ++mi)
#pragma unroll
      for (int ni = 0; ni < 4; ++ni)
#pragma unroll
        for (int r = 0; r < 4; ++r) {
          const float s = acc[mi][ni][r];
          const float e = exp2f(s);
          rsumv[mi][r] += e;
          colpart[ni] += e;
          if (hasPos) {
            const int rl = waveM * 64 + mi * 16 + quad * 4 + r;
            const int cl = waveN * 64 + ni * 16 + l15;
            if (cl == rl) posAcc += s;   // diagonal sim: pair (i, i+4096)
          }
        }
  }

  // transpose-store row partials: lane -> [waveN][waveM][l15][mi*16+quad*4 .. +3]
  {
    float* wbase = redBuf + ((waveN * 2 + waveM) * 16 + l15) * 68 + quad * 4;
#pragma unroll
    for (int mi = 0; mi < 4; ++mi)
      *(f32x4*)(wbase + mi * 16) = rsumv[mi];
  }

  // col sums (symmetry credit): reduce over quads, combine waveM pair in LDS
  if (!diagTile) {
#pragma unroll
    for (int ni = 0; ni < 4; ++ni) {
      float c = colpart[ni];
      c += __shfl_xor(c, 16, 64);
      c += __shfl_xor(c, 32, 64);
      if (quad == 0) atomicAdd(&colAcc[waveN * 64 + ni * 16 + l15], c);
    }
  }
  // positives: reduce in-wave, combine in LDS
  if (hasPos) {
    float p = posAcc;
#pragma unroll
    for (int m = 32; m > 0; m >>= 1) p += __shfl_xor(p, m, 64);
    if (lane == 0) atomicAdd(&posSh, p);
  }
  __syncthreads();

  // 256 threads: each sums one (row, waveN-half) = 16 strided floats
  {
    const int wn = tid >> 7, r = tid & 127;
    const int strip = r >> 6, rl = r & 63;
    const float* base = redBuf + ((wn * 2 + strip) * 16) * 68 + rl;
    float s = 0.0f;
#pragma unroll
    for (int j = 0; j < 16; ++j) s += base[j * 68];
    atomicAdd(&rowsum[rowBase + r], s);
  }
  if (tid < TILE && !diagTile)
    atomicAdd(&rowsum[colBase + tid], colAcc[tid]);
  if (tid == 0 && hasPos)
    atomicAdd(possimSum, 2.0f * posSh);   // each diag sim counts for 2 rows

  // --- completion counter: last block computes the loss ---
  // __syncthreads drains vmcnt(0): this block's device-scope atomics are
  // performed at the coherence point before the counter RMW below.
  __syncthreads();
  if (tid == 0)
    lastFlag = (atomicAdd(counter, 1) == NPAIR - 1) ? 1 : 0;
  __syncthreads();

  if (lastFlag) {
    // Plain coalesced loads (NOT atomic loads -- R7's 33us idle tail).
    // No stale-line hazard: see kernel comment. Compiler barrier stops
    // any hoisting above the counter RMW; HW order is guaranteed by the
    // control dependency on lastFlag.
    asm volatile("" ::: "memory");
    float av = 0.0f;
    const float4* rs4 = (const float4*)rowsum;
    for (int i = tid; i < BATCH / 4; i += 256) {
      const float4 v = rs4[i];
      av += __logf(v.x) + __logf(v.y) + __logf(v.z) + __logf(v.w);
    }
#pragma unroll
    for (int m = 32; m > 0; m >>= 1) av += __shfl_xor(av, m, 64);
    if (lane == 0) colAcc[wv] = av;      // colAcc dead; reuse for 4 wave sums
    __syncthreads();
    if (tid == 0) {
      const float tot = colAcc[0] + colAcc[1] + colAcc[2] + colAcc[3];
      out[0] = (tot - possimSum[0] * LN2) * (1.0f / (float)BATCH);
    }
  }
}

extern "C" void kernel_launch(void* const* d_in, const int* in_sizes, int n_in,
                              void* d_out, int out_size, void* d_ws, size_t ws_size,
                              hipStream_t stream) {
  const float* x = (const float*)d_in[0];
  float* out = (float*)d_out;

  __hip_bfloat16* Fb = (__hip_bfloat16*)d_ws;
  float* rowsum = (float*)((char*)d_ws + (size_t)BATCH * DIM * sizeof(__hip_bfloat16));
  float* possimSum = rowsum + BATCH;
  int* counter = (int*)(possimSum + 1);

  normalize_bf16<<<BATCH / 4, 256, 0, stream>>>(x, Fb, rowsum, possimSum, counter);
  sim_lse_kernel<<<NPAIR, 256, 0, stream>>>(Fb, rowsum, possimSum, counter, out);
}